// Round 5
// baseline (817.223 us; speedup 1.0000x reference)
//
#include <hip/hip_runtime.h>

#define B_    64
#define HID_  4096
#define HQ_   32
#define HKV_  8
#define D_    128
#define BS_   16
#define MAXB_ 64

#define KSPLIT  32
#define KCHUNK  (HID_ / KSPLIT)   // 128
#define QKV_ROWS 6144             // 4096 q + 1024 k + 1024 v
#define O_ROWS   4096
#define RPB     64                // rows per block in gemm_part
#define SPLITS  8                 // flash-decode token splits

// workspace layout (floats); big region reused sequentially:
//   phase 1: part1   [KSPLIT][QKV_ROWS][64]  (50 MB)
//   phase 2: part_o  [4096][512] + part_ml [4096][8]  (8.5 MB)
//   phase 3: part3   [KSPLIT][64][O_ROWS]   (33 MB)
#define PART1_SZ ((size_t)KSPLIT * QKV_ROWS * 64)
#define QKVF_SZ  ((size_t)64 * 6144)
#define ATTN_SZ  ((size_t)64 * 4096)

// ---------------------------------------------------------------------------
// Register-streaming skinny GEMM partial. No LDS, no barriers. VGPR ~52 ->
// 8 waves/SIMD. Grid supplies >=8 blocks/CU (KSPLIT=32) so latency is hidden
// by wave parallelism: each wave ~13% duty, 8 waves/SIMD ~= full VALU.
// tx=tid&15 owns batches 4tx..4tx+3; ty=tid>>4 owns rows r0+4ty..+3.
// bm=0: part[ks][row][64]   bm=1: part[ks][batch][rows_total]
// ---------------------------------------------------------------------------
__global__ __launch_bounds__(256, 8) void gemm_part(
    const float* __restrict__ X, const float* __restrict__ W0,
    const float* __restrict__ W1, const float* __restrict__ W2,
    int split1, int split2, int rows_total, int bm, float* __restrict__ part)
{
  const int tid = threadIdx.x;
  const int tx  = tid & 15;
  const int ty  = tid >> 4;
  const int r0  = blockIdx.x * RPB;
  const int k0  = blockIdx.y * KCHUNK;

  const float* W; int rloc;
  if (r0 < split1)      { W = W0; rloc = r0; }
  else if (r0 < split2) { W = W1; rloc = r0 - split1; }
  else                  { W = W2; rloc = r0 - split2; }

  const float* wrow = W + (size_t)(rloc + 4 * ty) * HID_ + k0;
  const float* xrow = X + (size_t)(4 * tx) * HID_ + k0;

  float acc[4][4];
  #pragma unroll
  for (int i = 0; i < 4; ++i)
    #pragma unroll
    for (int j = 0; j < 4; ++j) acc[i][j] = 0.f;

  #pragma unroll 2
  for (int k = 0; k < KCHUNK; k += 4) {
    float4 wv[4], xv[4];
    #pragma unroll
    for (int i = 0; i < 4; ++i)
      wv[i] = *(const float4*)(wrow + (size_t)i * HID_ + k);
    #pragma unroll
    for (int j = 0; j < 4; ++j)
      xv[j] = *(const float4*)(xrow + (size_t)j * HID_ + k);
    #pragma unroll
    for (int i = 0; i < 4; ++i)
      #pragma unroll
      for (int j = 0; j < 4; ++j)
        acc[i][j] += wv[i].x * xv[j].x + wv[i].y * xv[j].y
                   + wv[i].z * xv[j].z + wv[i].w * xv[j].w;
  }

  if (!bm) {
    float* base = part + ((size_t)blockIdx.y * rows_total + r0 + 4 * ty) * 64 + 4 * tx;
    #pragma unroll
    for (int i = 0; i < 4; ++i)
      *(float4*)(base + (size_t)i * 64) =
          make_float4(acc[i][0], acc[i][1], acc[i][2], acc[i][3]);
  } else {
    float* base = part + ((size_t)blockIdx.y * 64 + 4 * tx) * rows_total + r0 + 4 * ty;
    #pragma unroll
    for (int j = 0; j < 4; ++j)
      *(float4*)(base + (size_t)j * rows_total) =
          make_float4(acc[0][j], acc[1][j], acc[2][j], acc[3][j]);
  }
}

// ---------------------------------------------------------------------------
// Sum K-split partials + RoPE (half-split). q scaled by 1/sqrt(D).
// qkvf layout: q[64][32][128] | k[64][8][128] | v[64][8][128]
// ---------------------------------------------------------------------------
__global__ __launch_bounds__(256) void reduce_rope(
    const float* __restrict__ part, const float* __restrict__ cosT,
    const float* __restrict__ sinT, const int* __restrict__ positions,
    float* __restrict__ qkvf)
{
  const int bb  = threadIdx.x & 63;
  const int cid = blockIdx.x * 4 + (threadIdx.x >> 6);  // 0..3071
  const int pos = positions[bb];

  if (cid < 2048) {                       // q pairs: (hq, d0)
    const int hq = cid >> 6, d0 = cid & 63;
    const int r1 = hq * 128 + d0;
    float x1 = 0.f, x2 = 0.f;
    #pragma unroll 8
    for (int ks = 0; ks < KSPLIT; ++ks) {
      x1 += part[((size_t)ks * QKV_ROWS + r1) * 64 + bb];
      x2 += part[((size_t)ks * QKV_ROWS + r1 + 64) * 64 + bb];
    }
    float c = cosT[pos * 64 + d0], s = sinT[pos * 64 + d0];
    const float scale = 0.08838834764831843f;   // 1/sqrt(128)
    qkvf[(size_t)(bb * 32 + hq) * 128 + d0]      = (x1 * c - x2 * s) * scale;
    qkvf[(size_t)(bb * 32 + hq) * 128 + d0 + 64] = (x2 * c + x1 * s) * scale;
  } else if (cid < 2560) {                // k pairs
    const int c2 = cid - 2048;
    const int kh = c2 >> 6, d0 = c2 & 63;
    const int r1 = 4096 + kh * 128 + d0;
    float x1 = 0.f, x2 = 0.f;
    #pragma unroll 8
    for (int ks = 0; ks < KSPLIT; ++ks) {
      x1 += part[((size_t)ks * QKV_ROWS + r1) * 64 + bb];
      x2 += part[((size_t)ks * QKV_ROWS + r1 + 64) * 64 + bb];
    }
    float c = cosT[pos * 64 + d0], s = sinT[pos * 64 + d0];
    qkvf[262144 + (size_t)(bb * 8 + kh) * 128 + d0]      = x1 * c - x2 * s;
    qkvf[262144 + (size_t)(bb * 8 + kh) * 128 + d0 + 64] = x2 * c + x1 * s;
  } else {                                // v passthrough
    const int c2 = cid - 2560;
    const int kh = c2 >> 6, d0 = c2 & 63;
    const int r1 = 5120 + kh * 128 + d0;
    float x1 = 0.f, x2 = 0.f;
    #pragma unroll 8
    for (int ks = 0; ks < KSPLIT; ++ks) {
      x1 += part[((size_t)ks * QKV_ROWS + r1) * 64 + bb];
      x2 += part[((size_t)ks * QKV_ROWS + r1 + 64) * 64 + bb];
    }
    qkvf[327680 + (size_t)(bb * 8 + kh) * 128 + d0]      = x1;
    qkvf[327680 + (size_t)(bb * 8 + kh) * 128 + d0 + 64] = x2;
  }
}

// ---------------------------------------------------------------------------
// Flash-decode split attention: block = (b, h, split s). Each split handles
// chunk = ceil(ctx/8) tokens, emits unnormalized partial (m, l, sum pV).
// Token t == ctx-1 substitutes freshly-roped k/v (virtual cache scatter).
// ---------------------------------------------------------------------------
__global__ __launch_bounds__(256) void attn_split(
    const float* __restrict__ qkvf, const float* __restrict__ kcache,
    const float* __restrict__ vcache, const int* __restrict__ btab,
    const int* __restrict__ ctxlen,
    float* __restrict__ part_o,   // [B*HKV*SPLITS][4][128]
    float* __restrict__ part_ml)  // [B*HKV*SPLITS][4][2]
{
  const int bid = blockIdx.x;
  const int s   = bid & (SPLITS - 1);
  const int bh  = bid >> 3;
  const int b = bh >> 3, h = bh & 7;
  const int ctx   = ctxlen[b];
  const int chunk = (ctx + SPLITS - 1) / SPLITS;   // <= 128
  const int t0 = s * chunk;
  const int t1 = min(ctx, t0 + chunk);
  const int n  = t1 - t0;
  const int last = ctx - 1;

  const int tid  = threadIdx.x;
  const int half = tid >> 5;     // 0..7
  const int d4   = tid & 31;

  __shared__ float sc[4][128];
  __shared__ float oacc[8][4][128];
  __shared__ float red[4][2];    // m, l per group-head

  float4 qf[4];
  #pragma unroll
  for (int g = 0; g < 4; ++g)
    qf[g] = *(const float4*)(qkvf + (size_t)(b * 32 + h * 4 + g) * 128 + d4 * 4);

  const float* knew = qkvf + 262144 + (size_t)(b * 8 + h) * 128;
  const float* vnew = qkvf + 327680 + (size_t)(b * 8 + h) * 128;

  // ---- pass 1: scores for this chunk
  for (int t = t0 + half; t < t1; t += 8) {
    const float* kp;
    if (t == last) kp = knew;
    else {
      int slot = btab[b * MAXB_ + (t >> 4)] * BS_ + (t & 15);
      kp = kcache + ((size_t)slot * HKV_ + h) * D_;
    }
    float4 kv = *(const float4*)(kp + d4 * 4);
    float p0 = qf[0].x * kv.x + qf[0].y * kv.y + qf[0].z * kv.z + qf[0].w * kv.w;
    float p1 = qf[1].x * kv.x + qf[1].y * kv.y + qf[1].z * kv.z + qf[1].w * kv.w;
    float p2 = qf[2].x * kv.x + qf[2].y * kv.y + qf[2].z * kv.z + qf[2].w * kv.w;
    float p3 = qf[3].x * kv.x + qf[3].y * kv.y + qf[3].z * kv.z + qf[3].w * kv.w;
    #pragma unroll
    for (int m = 16; m >= 1; m >>= 1) {
      p0 += __shfl_xor(p0, m);
      p1 += __shfl_xor(p1, m);
      p2 += __shfl_xor(p2, m);
      p3 += __shfl_xor(p3, m);
    }
    if (d4 == 0) {
      int i = t - t0;
      sc[0][i] = p0; sc[1][i] = p1; sc[2][i] = p2; sc[3][i] = p3;
    }
  }
  __syncthreads();

  // ---- partial softmax: wave w handles group-head g = w
  {
    const int w = tid >> 6, l = tid & 63;
    float mx = -1e30f;
    for (int i = l; i < n; i += 64) mx = fmaxf(mx, sc[w][i]);
    #pragma unroll
    for (int m = 32; m >= 1; m >>= 1) mx = fmaxf(mx, __shfl_xor(mx, m));
    float lsum = 0.f;
    for (int i = l; i < n; i += 64) {
      float p = __expf(sc[w][i] - mx);
      sc[w][i] = p;
      lsum += p;
    }
    #pragma unroll
    for (int m = 32; m >= 1; m >>= 1) lsum += __shfl_xor(lsum, m);
    if (l == 0) { red[w][0] = mx; red[w][1] = lsum; }
  }
  __syncthreads();

  // ---- pass 2: sum p*V (unnormalized)
  float acc[4][4] = {{0.f}};
  for (int t = t0 + half; t < t1; t += 8) {
    const float* vp;
    if (t == last) vp = vnew;
    else {
      int slot = btab[b * MAXB_ + (t >> 4)] * BS_ + (t & 15);
      vp = vcache + ((size_t)slot * HKV_ + h) * D_;
    }
    float4 vv = *(const float4*)(vp + d4 * 4);
    int i = t - t0;
    #pragma unroll
    for (int g = 0; g < 4; ++g) {
      float p = sc[g][i];
      acc[g][0] += p * vv.x; acc[g][1] += p * vv.y;
      acc[g][2] += p * vv.z; acc[g][3] += p * vv.w;
    }
  }
  #pragma unroll
  for (int g = 0; g < 4; ++g)
    #pragma unroll
    for (int j = 0; j < 4; ++j)
      oacc[half][g][d4 * 4 + j] = acc[g][j];
  __syncthreads();

  for (int idx = tid; idx < 512; idx += 256) {
    int g = idx >> 7, d = idx & 127;
    float v = 0.f;
    #pragma unroll
    for (int hh = 0; hh < 8; ++hh) v += oacc[hh][g][d];
    part_o[(size_t)bid * 512 + idx] = v;
  }
  if (tid < 8) part_ml[(size_t)bid * 8 + tid] = red[tid >> 1][tid & 1];
}

// ---------------------------------------------------------------------------
// Combine split partials: out = sum_s exp(m_s-M) o_s / sum_s exp(m_s-M) l_s
// ---------------------------------------------------------------------------
__global__ __launch_bounds__(256) void attn_combine(
    const float* __restrict__ part_o, const float* __restrict__ part_ml,
    float* __restrict__ attn_out)
{
  const int bh = blockIdx.x;            // 0..511
  const int tid = threadIdx.x;

  __shared__ float Sg[SPLITS][4];
  __shared__ float Dg[4];

  if (tid < 32) {                       // lane = s*4+g
    int s = tid >> 2, g = tid & 3;
    float m = part_ml[((size_t)bh * SPLITS + s) * 8 + g * 2];
    float l = part_ml[((size_t)bh * SPLITS + s) * 8 + g * 2 + 1];
    float M = m;
    #pragma unroll
    for (int k = 4; k <= 16; k <<= 1) M = fmaxf(M, __shfl_xor(M, k));
    float scl = __expf(m - M);
    float dl = l * scl;
    #pragma unroll
    for (int k = 4; k <= 16; k <<= 1) dl += __shfl_xor(dl, k);
    Sg[s][g] = scl;
    if (s == 0) Dg[g] = dl;
  }
  __syncthreads();

  for (int idx = tid; idx < 512; idx += 256) {
    int g = idx >> 7;
    float num = 0.f;
    #pragma unroll
    for (int s = 0; s < SPLITS; ++s)
      num += Sg[s][g] * part_o[((size_t)bh * SPLITS + s) * 512 + idx];
    attn_out[(size_t)bh * 512 + idx] = num / Dg[g];
  }
}

// ---------------------------------------------------------------------------
// part3 is batch-major: [ks][batch][4096 rows] -> fully coalesced both sides
// ---------------------------------------------------------------------------
__global__ __launch_bounds__(256) void reduce_out(
    const float* __restrict__ part, float* __restrict__ out)
{
  int o  = blockIdx.x * 256 + threadIdx.x;  // 0..262143
  int bb = o >> 12, i = o & 4095;
  float s = 0.f;
  #pragma unroll 8
  for (int ks = 0; ks < KSPLIT; ++ks)
    s += part[((size_t)ks * 64 + bb) * O_ROWS + i];
  out[o] = s;
}

// ---------------------------------------------------------------------------
extern "C" void kernel_launch(void* const* d_in, const int* in_sizes, int n_in,
                              void* d_out, int out_size, void* d_ws, size_t ws_size,
                              hipStream_t stream)
{
  (void)in_sizes; (void)n_in; (void)out_size; (void)ws_size;
  const float* hidden    = (const float*)d_in[0];
  const int*   positions = (const int*)d_in[1];
  const float* cosT      = (const float*)d_in[2];
  const float* sinT      = (const float*)d_in[3];
  const float* kcache    = (const float*)d_in[4];
  const float* vcache    = (const float*)d_in[5];
  const int*   btab      = (const int*)d_in[7];
  const int*   ctx       = (const int*)d_in[8];
  const float* Wq        = (const float*)d_in[9];
  const float* Wk        = (const float*)d_in[10];
  const float* Wv        = (const float*)d_in[11];
  const float* Wo        = (const float*)d_in[12];
  float* out = (float*)d_out;

  float* ws     = (float*)d_ws;
  float* region = ws;                       // 50 MB region, reused 3x
  float* qkvf   = region + PART1_SZ;
  float* attn_o = qkvf + QKVF_SZ;
  // phase 1
  float* part1  = region;
  // phase 2 (after reduce_rope, part1 dead)
  float* part_o  = region;                                     // 4096*512
  float* part_ml = region + (size_t)B_ * HKV_ * SPLITS * 512;  // 4096*8
  // phase 3 (after attn_combine, part_o dead)
  float* part3  = region;

  gemm_part<<<dim3(QKV_ROWS / RPB, KSPLIT), 256, 0, stream>>>(
      hidden, Wq, Wk, Wv, 4096, 5120, QKV_ROWS, 0, part1);
  reduce_rope<<<768, 256, 0, stream>>>(part1, cosT, sinT, positions, qkvf);
  attn_split<<<B_ * HKV_ * SPLITS, 256, 0, stream>>>(
      qkvf, kcache, vcache, btab, ctx, part_o, part_ml);
  attn_combine<<<B_ * HKV_, 256, 0, stream>>>(part_o, part_ml, attn_o);
  gemm_part<<<dim3(O_ROWS / RPB, KSPLIT), 256, 0, stream>>>(
      attn_o, Wo, Wo, Wo, O_ROWS, O_ROWS, O_ROWS, 1, part3);
  reduce_out<<<1024, 256, 0, stream>>>(part3, out);
}

// Round 6
// 618.393 us; speedup vs baseline: 1.3215x; 1.3215x over previous
//
#include <hip/hip_runtime.h>

#define B_    64
#define HID_  4096
#define HQ_   32
#define HKV_  8
#define D_    128
#define BS_   16
#define MAXB_ 64

#define KSPLIT  32
#define KCHUNK  (HID_ / KSPLIT)   // 128
#define QKV_ROWS 6144             // 4096 q + 1024 k + 1024 v
#define O_ROWS   4096
#define SPLITS  8                 // flash-decode token splits

// workspace layout (floats); big region reused sequentially:
//   phase 1: part1   [KSPLIT][QKV_ROWS][64]  (50 MB)
//   phase 2: part_o  [4096][512] + part_ml [4096][8]  (8.5 MB)
//   phase 3: part3   [KSPLIT][O_ROWS][64]    (33 MB)
#define REGION_SZ ((size_t)KSPLIT * QKV_ROWS * 64)
#define QKVF_SZ  ((size_t)64 * 6144)
#define ATTN_SZ  ((size_t)64 * 4096)
#define XT_SZ    ((size_t)64 * 4096)

// ---------------------------------------------------------------------------
// Transpose [64][N] -> [N][64] via LDS tile (conflict-free, coalesced both
// sides). Used for hidden and attn output so gemm_sk reads X^T[k][batch].
// ---------------------------------------------------------------------------
__global__ __launch_bounds__(256) void transpose64(
    const float* __restrict__ in, float* __restrict__ outT, int N)
{
  __shared__ float t[64][65];
  const int c0 = blockIdx.x * 64;
  const int lane = threadIdx.x & 63, q = threadIdx.x >> 6;
  #pragma unroll
  for (int r = q; r < 64; r += 4)
    t[r][lane] = in[(size_t)r * N + c0 + lane];
  __syncthreads();
  #pragma unroll
  for (int r = q; r < 64; r += 4)
    outT[(size_t)(c0 + r) * 64 + lane] = t[lane][r];
}

// ---------------------------------------------------------------------------
// Scalar-W skinny GEMM partial. lane = batch (N=64 = wave size).
// Wave owns 32 W-rows; W[row][k] is wave-uniform -> s_load via scalar cache
// (sequential 64B lines, read exactly once). X^T[k][0..63] is one coalesced
// 256B vector load per k, every byte used. acc = 32 VGPR.
// part[ks][row][64batch].
// ---------------------------------------------------------------------------
__global__ __launch_bounds__(256, 4) void gemm_sk(
    const float* __restrict__ XT, const float* __restrict__ W0,
    const float* __restrict__ W1, const float* __restrict__ W2,
    int split1, int split2, int rows_total, float* __restrict__ part)
{
  const int lane = threadIdx.x & 63;
  const int wid  = __builtin_amdgcn_readfirstlane(threadIdx.x >> 6);  // 0..3
  const int r0   = blockIdx.x * 128 + wid * 32;
  const int k0   = blockIdx.y * KCHUNK;

  const float* W; int rloc;
  if (r0 < split1)      { W = W0; rloc = r0; }
  else if (r0 < split2) { W = W1; rloc = r0 - split1; }
  else                  { W = W2; rloc = r0 - split2; }

  const float* wb = W + (size_t)rloc * HID_ + k0;   // wave-uniform
  const float* xb = XT + (size_t)k0 * 64 + lane;    // per-lane batch column

  float acc[32];
  #pragma unroll
  for (int r = 0; r < 32; ++r) acc[r] = 0.f;

  #pragma unroll 2
  for (int k = 0; k < KCHUNK; k += 4) {
    float x0 = xb[(size_t)(k + 0) * 64];
    float x1 = xb[(size_t)(k + 1) * 64];
    float x2 = xb[(size_t)(k + 2) * 64];
    float x3 = xb[(size_t)(k + 3) * 64];
    #pragma unroll
    for (int r = 0; r < 32; ++r) {
      const float* wr = wb + (size_t)r * HID_ + k;  // uniform -> s_load
      float a = acc[r];
      a = fmaf(wr[0], x0, a);
      a = fmaf(wr[1], x1, a);
      a = fmaf(wr[2], x2, a);
      a = fmaf(wr[3], x3, a);
      acc[r] = a;
    }
  }

  float* base = part + ((size_t)blockIdx.y * rows_total + r0) * 64 + lane;
  #pragma unroll
  for (int r = 0; r < 32; ++r) base[(size_t)r * 64] = acc[r];  // 256B/instr
}

// ---------------------------------------------------------------------------
// Sum K-split partials + RoPE (half-split). q scaled by 1/sqrt(D).
// qkvf layout: q[64][32][128] | k[64][8][128] | v[64][8][128]
// ---------------------------------------------------------------------------
__global__ __launch_bounds__(256) void reduce_rope(
    const float* __restrict__ part, const float* __restrict__ cosT,
    const float* __restrict__ sinT, const int* __restrict__ positions,
    float* __restrict__ qkvf)
{
  const int bb  = threadIdx.x & 63;
  const int cid = blockIdx.x * 4 + (threadIdx.x >> 6);  // 0..3071
  const int pos = positions[bb];

  if (cid < 2048) {                       // q pairs: (hq, d0)
    const int hq = cid >> 6, d0 = cid & 63;
    const int r1 = hq * 128 + d0;
    float x1 = 0.f, x2 = 0.f;
    #pragma unroll 8
    for (int ks = 0; ks < KSPLIT; ++ks) {
      x1 += part[((size_t)ks * QKV_ROWS + r1) * 64 + bb];
      x2 += part[((size_t)ks * QKV_ROWS + r1 + 64) * 64 + bb];
    }
    float c = cosT[pos * 64 + d0], s = sinT[pos * 64 + d0];
    const float scale = 0.08838834764831843f;   // 1/sqrt(128)
    qkvf[(size_t)(bb * 32 + hq) * 128 + d0]      = (x1 * c - x2 * s) * scale;
    qkvf[(size_t)(bb * 32 + hq) * 128 + d0 + 64] = (x2 * c + x1 * s) * scale;
  } else if (cid < 2560) {                // k pairs
    const int c2 = cid - 2048;
    const int kh = c2 >> 6, d0 = c2 & 63;
    const int r1 = 4096 + kh * 128 + d0;
    float x1 = 0.f, x2 = 0.f;
    #pragma unroll 8
    for (int ks = 0; ks < KSPLIT; ++ks) {
      x1 += part[((size_t)ks * QKV_ROWS + r1) * 64 + bb];
      x2 += part[((size_t)ks * QKV_ROWS + r1 + 64) * 64 + bb];
    }
    float c = cosT[pos * 64 + d0], s = sinT[pos * 64 + d0];
    qkvf[262144 + (size_t)(bb * 8 + kh) * 128 + d0]      = x1 * c - x2 * s;
    qkvf[262144 + (size_t)(bb * 8 + kh) * 128 + d0 + 64] = x2 * c + x1 * s;
  } else {                                // v passthrough
    const int c2 = cid - 2560;
    const int kh = c2 >> 6, d0 = c2 & 63;
    const int r1 = 5120 + kh * 128 + d0;
    float x1 = 0.f, x2 = 0.f;
    #pragma unroll 8
    for (int ks = 0; ks < KSPLIT; ++ks) {
      x1 += part[((size_t)ks * QKV_ROWS + r1) * 64 + bb];
      x2 += part[((size_t)ks * QKV_ROWS + r1 + 64) * 64 + bb];
    }
    qkvf[327680 + (size_t)(bb * 8 + kh) * 128 + d0]      = x1;
    qkvf[327680 + (size_t)(bb * 8 + kh) * 128 + d0 + 64] = x2;
  }
}

// ---------------------------------------------------------------------------
// Flash-decode split attention: block = (b, h, split s). Each split handles
// chunk = ceil(ctx/8) tokens, emits unnormalized partial (m, l, sum pV).
// Token t == ctx-1 substitutes freshly-roped k/v (virtual cache scatter).
// ---------------------------------------------------------------------------
__global__ __launch_bounds__(256) void attn_split(
    const float* __restrict__ qkvf, const float* __restrict__ kcache,
    const float* __restrict__ vcache, const int* __restrict__ btab,
    const int* __restrict__ ctxlen,
    float* __restrict__ part_o,   // [B*HKV*SPLITS][4][128]
    float* __restrict__ part_ml)  // [B*HKV*SPLITS][4][2]
{
  const int bid = blockIdx.x;
  const int s   = bid & (SPLITS - 1);
  const int bh  = bid >> 3;
  const int b = bh >> 3, h = bh & 7;
  const int ctx   = ctxlen[b];
  const int chunk = (ctx + SPLITS - 1) / SPLITS;   // <= 128
  const int t0 = s * chunk;
  const int t1 = min(ctx, t0 + chunk);
  const int n  = t1 - t0;
  const int last = ctx - 1;

  const int tid  = threadIdx.x;
  const int half = tid >> 5;     // 0..7
  const int d4   = tid & 31;

  __shared__ float sc[4][128];
  __shared__ float oacc[8][4][128];
  __shared__ float red[4][2];    // m, l per group-head

  float4 qf[4];
  #pragma unroll
  for (int g = 0; g < 4; ++g)
    qf[g] = *(const float4*)(qkvf + (size_t)(b * 32 + h * 4 + g) * 128 + d4 * 4);

  const float* knew = qkvf + 262144 + (size_t)(b * 8 + h) * 128;
  const float* vnew = qkvf + 327680 + (size_t)(b * 8 + h) * 128;

  // ---- pass 1: scores for this chunk
  for (int t = t0 + half; t < t1; t += 8) {
    const float* kp;
    if (t == last) kp = knew;
    else {
      int slot = btab[b * MAXB_ + (t >> 4)] * BS_ + (t & 15);
      kp = kcache + ((size_t)slot * HKV_ + h) * D_;
    }
    float4 kv = *(const float4*)(kp + d4 * 4);
    float p0 = qf[0].x * kv.x + qf[0].y * kv.y + qf[0].z * kv.z + qf[0].w * kv.w;
    float p1 = qf[1].x * kv.x + qf[1].y * kv.y + qf[1].z * kv.z + qf[1].w * kv.w;
    float p2 = qf[2].x * kv.x + qf[2].y * kv.y + qf[2].z * kv.z + qf[2].w * kv.w;
    float p3 = qf[3].x * kv.x + qf[3].y * kv.y + qf[3].z * kv.z + qf[3].w * kv.w;
    #pragma unroll
    for (int m = 16; m >= 1; m >>= 1) {
      p0 += __shfl_xor(p0, m);
      p1 += __shfl_xor(p1, m);
      p2 += __shfl_xor(p2, m);
      p3 += __shfl_xor(p3, m);
    }
    if (d4 == 0) {
      int i = t - t0;
      sc[0][i] = p0; sc[1][i] = p1; sc[2][i] = p2; sc[3][i] = p3;
    }
  }
  __syncthreads();

  // ---- partial softmax: wave w handles group-head g = w
  {
    const int w = tid >> 6, l = tid & 63;
    float mx = -1e30f;
    for (int i = l; i < n; i += 64) mx = fmaxf(mx, sc[w][i]);
    #pragma unroll
    for (int m = 32; m >= 1; m >>= 1) mx = fmaxf(mx, __shfl_xor(mx, m));
    float lsum = 0.f;
    for (int i = l; i < n; i += 64) {
      float p = __expf(sc[w][i] - mx);
      sc[w][i] = p;
      lsum += p;
    }
    #pragma unroll
    for (int m = 32; m >= 1; m >>= 1) lsum += __shfl_xor(lsum, m);
    if (l == 0) { red[w][0] = mx; red[w][1] = lsum; }
  }
  __syncthreads();

  // ---- pass 2: sum p*V (unnormalized)
  float acc[4][4] = {{0.f}};
  for (int t = t0 + half; t < t1; t += 8) {
    const float* vp;
    if (t == last) vp = vnew;
    else {
      int slot = btab[b * MAXB_ + (t >> 4)] * BS_ + (t & 15);
      vp = vcache + ((size_t)slot * HKV_ + h) * D_;
    }
    float4 vv = *(const float4*)(vp + d4 * 4);
    int i = t - t0;
    #pragma unroll
    for (int g = 0; g < 4; ++g) {
      float p = sc[g][i];
      acc[g][0] += p * vv.x; acc[g][1] += p * vv.y;
      acc[g][2] += p * vv.z; acc[g][3] += p * vv.w;
    }
  }
  #pragma unroll
  for (int g = 0; g < 4; ++g)
    #pragma unroll
    for (int j = 0; j < 4; ++j)
      oacc[half][g][d4 * 4 + j] = acc[g][j];
  __syncthreads();

  for (int idx = tid; idx < 512; idx += 256) {
    int g = idx >> 7, d = idx & 127;
    float v = 0.f;
    #pragma unroll
    for (int hh = 0; hh < 8; ++hh) v += oacc[hh][g][d];
    part_o[(size_t)bid * 512 + idx] = v;
  }
  if (tid < 8) part_ml[(size_t)bid * 8 + tid] = red[tid >> 1][tid & 1];
}

// ---------------------------------------------------------------------------
// Combine split partials: out = sum_s exp(m_s-M) o_s / sum_s exp(m_s-M) l_s
// ---------------------------------------------------------------------------
__global__ __launch_bounds__(256) void attn_combine(
    const float* __restrict__ part_o, const float* __restrict__ part_ml,
    float* __restrict__ attn_out)
{
  const int bh = blockIdx.x;            // 0..511
  const int tid = threadIdx.x;

  __shared__ float Sg[SPLITS][4];
  __shared__ float Dg[4];

  if (tid < 32) {                       // lane = s*4+g
    int s = tid >> 2, g = tid & 3;
    float m = part_ml[((size_t)bh * SPLITS + s) * 8 + g * 2];
    float l = part_ml[((size_t)bh * SPLITS + s) * 8 + g * 2 + 1];
    float M = m;
    #pragma unroll
    for (int k = 4; k <= 16; k <<= 1) M = fmaxf(M, __shfl_xor(M, k));
    float scl = __expf(m - M);
    float dl = l * scl;
    #pragma unroll
    for (int k = 4; k <= 16; k <<= 1) dl += __shfl_xor(dl, k);
    Sg[s][g] = scl;
    if (s == 0) Dg[g] = dl;
  }
  __syncthreads();

  for (int idx = tid; idx < 512; idx += 256) {
    int g = idx >> 7;
    float num = 0.f;
    #pragma unroll
    for (int s = 0; s < SPLITS; ++s)
      num += Sg[s][g] * part_o[((size_t)bh * SPLITS + s) * 512 + idx];
    attn_out[(size_t)bh * 512 + idx] = num / Dg[g];
  }
}

// ---------------------------------------------------------------------------
// Sum K-split partials of O-GEMM ([ks][row][batch]) and write out[b][row]
// via LDS transpose: all global reads/writes coalesced.
// ---------------------------------------------------------------------------
__global__ __launch_bounds__(256) void reduce_out_t(
    const float* __restrict__ part, float* __restrict__ out)
{
  __shared__ float t[64][65];
  const int i0 = blockIdx.x * 64;
  const int lane = threadIdx.x & 63, q = threadIdx.x >> 6;

  #pragma unroll
  for (int rr = q; rr < 64; rr += 4) {
    float s = 0.f;
    #pragma unroll 8
    for (int ks = 0; ks < KSPLIT; ++ks)
      s += part[((size_t)ks * O_ROWS + i0 + rr) * 64 + lane];
    t[rr][lane] = s;
  }
  __syncthreads();
  #pragma unroll
  for (int rr = q; rr < 64; rr += 4)
    out[(size_t)rr * O_ROWS + i0 + lane] = t[lane][rr];
}

// ---------------------------------------------------------------------------
extern "C" void kernel_launch(void* const* d_in, const int* in_sizes, int n_in,
                              void* d_out, int out_size, void* d_ws, size_t ws_size,
                              hipStream_t stream)
{
  (void)in_sizes; (void)n_in; (void)out_size; (void)ws_size;
  const float* hidden    = (const float*)d_in[0];
  const int*   positions = (const int*)d_in[1];
  const float* cosT      = (const float*)d_in[2];
  const float* sinT      = (const float*)d_in[3];
  const float* kcache    = (const float*)d_in[4];
  const float* vcache    = (const float*)d_in[5];
  const int*   btab      = (const int*)d_in[7];
  const int*   ctx       = (const int*)d_in[8];
  const float* Wq        = (const float*)d_in[9];
  const float* Wk        = (const float*)d_in[10];
  const float* Wv        = (const float*)d_in[11];
  const float* Wo        = (const float*)d_in[12];
  float* out = (float*)d_out;

  float* ws      = (float*)d_ws;
  float* region  = ws;                       // 50 MB region, reused 3x
  float* qkvf    = region + REGION_SZ;
  float* attn_o  = qkvf + QKVF_SZ;
  float* hiddenT = attn_o + ATTN_SZ;
  float* attn_oT = hiddenT + XT_SZ;
  // phase 1
  float* part1   = region;
  // phase 2 (after reduce_rope, part1 dead)
  float* part_o  = region;                                     // 4096*512
  float* part_ml = region + (size_t)B_ * HKV_ * SPLITS * 512;  // 4096*8
  // phase 3 (after attn_combine, part_o dead)
  float* part3   = region;

  transpose64<<<HID_ / 64, 256, 0, stream>>>(hidden, hiddenT, HID_);
  gemm_sk<<<dim3(QKV_ROWS / 128, KSPLIT), 256, 0, stream>>>(
      hiddenT, Wq, Wk, Wv, 4096, 5120, QKV_ROWS, part1);
  reduce_rope<<<768, 256, 0, stream>>>(part1, cosT, sinT, positions, qkvf);
  attn_split<<<B_ * HKV_ * SPLITS, 256, 0, stream>>>(
      qkvf, kcache, vcache, btab, ctx, part_o, part_ml);
  attn_combine<<<B_ * HKV_, 256, 0, stream>>>(part_o, part_ml, attn_o);
  transpose64<<<O_ROWS / 64, 256, 0, stream>>>(attn_o, attn_oT, O_ROWS);
  gemm_sk<<<dim3(O_ROWS / 128, KSPLIT), 256, 0, stream>>>(
      attn_oT, Wo, Wo, Wo, O_ROWS, O_ROWS, O_ROWS, part3);
  reduce_out_t<<<O_ROWS / 64, 256, 0, stream>>>(part3, out);
}

// Round 7
// 325.309 us; speedup vs baseline: 2.5121x; 1.9009x over previous
//
#include <hip/hip_runtime.h>

#define B_    64
#define HID_  4096
#define HQ_   32
#define HKV_  8
#define D_    128
#define BS_   16
#define MAXB_ 64

#define KSPLIT  16
#define KCHUNK  (HID_ / KSPLIT)   // 256
#define BK      32
#define NSTEPS  (KCHUNK / BK)     // 8
#define QKV_ROWS 6144             // 4096 q + 1024 k + 1024 v
#define O_ROWS   4096
#define SPLITS  8                 // flash-decode token splits

// workspace (floats); big region reused sequentially:
//   phase 1: part1 [KSPLIT][QKV_ROWS][64] (25MB) | phase 2: attn partials |
//   phase 3: part3 [KSPLIT][O_ROWS][64] (17MB)
#define REGION_SZ ((size_t)KSPLIT * QKV_ROWS * 64)
#define QKVF_SZ  ((size_t)64 * 6144)
#define ATTN_SZ  ((size_t)64 * 4096)
#define XT_SZ    ((size_t)64 * 4096)

// ---------------------------------------------------------------------------
// Transpose [64][N] -> [N][64] via LDS tile (coalesced both sides).
// ---------------------------------------------------------------------------
__global__ __launch_bounds__(256) void transpose64(
    const float* __restrict__ in, float* __restrict__ outT, int N)
{
  __shared__ float t[64][65];
  const int c0 = blockIdx.x * 64;
  const int lane = threadIdx.x & 63, q = threadIdx.x >> 6;
  #pragma unroll
  for (int r = q; r < 64; r += 4)
    t[r][lane] = in[(size_t)r * N + c0 + lane];
  __syncthreads();
  #pragma unroll
  for (int r = q; r < 64; r += 4)
    outT[(size_t)(c0 + r) * 64 + lane] = t[lane][r];
}

// ---------------------------------------------------------------------------
// LDS-broadcast skinny GEMM partial. lane = batch. Per BK=32 step:
//  - stage W[64][32] (8KB) + XT[32][64] (8KB) to LDS, coalesced, prefetched
//    into 16 VGPRs so global latency overlaps previous step's compute.
//  - wave wv computes rows r0+16wv..+16: W read as wave-uniform ds_read_b128
//    (broadcast, conflict-free); X read stride-1 (2-way, free).
// part[ks][row][64batch]. ~80 VGPR -> 4 waves/SIMD.
// ---------------------------------------------------------------------------
__global__ __launch_bounds__(256, 4) void gemm_lds(
    const float* __restrict__ XT, const float* __restrict__ W0,
    const float* __restrict__ W1, const float* __restrict__ W2,
    int split1, int split2, int rows_total, float* __restrict__ part)
{
  __shared__ float Wt[64 * 32];
  __shared__ float Xs[32 * 64];

  const int tid  = threadIdx.x;
  const int lane = tid & 63;
  const int wv   = tid >> 6;          // 0..3
  const int r0   = blockIdx.x * 64;
  const int k0   = blockIdx.y * KCHUNK;

  const float* W; int rloc;
  if (r0 < split1)      { W = W0; rloc = r0; }
  else if (r0 < split2) { W = W1; rloc = r0 - split1; }
  else                  { W = W2; rloc = r0 - split2; }

  const float* Wb = W + (size_t)rloc * HID_ + k0;

  const int wrow = tid >> 3;          // 0..31 (+32 for second chunk)
  const int wcol = (tid & 7) * 4;
  const int xk   = tid >> 4;          // 0..15 (+16 for second chunk)
  const int xb   = (tid & 15) * 4;

  float4 wst0, wst1, xst0, xst1;
  auto LOADG = [&](int ks) {
    wst0 = *(const float4*)(Wb + (size_t)wrow * HID_ + ks + wcol);
    wst1 = *(const float4*)(Wb + (size_t)(wrow + 32) * HID_ + ks + wcol);
    xst0 = *(const float4*)(XT + (size_t)(k0 + ks + xk) * 64 + xb);
    xst1 = *(const float4*)(XT + (size_t)(k0 + ks + xk + 16) * 64 + xb);
  };

  float acc[16];
  #pragma unroll
  for (int r = 0; r < 16; ++r) acc[r] = 0.f;

  LOADG(0);
  for (int s = 0; s < NSTEPS; ++s) {
    __syncthreads();                    // previous compute done
    *(float4*)&Wt[wrow * 32 + wcol]        = wst0;
    *(float4*)&Wt[(wrow + 32) * 32 + wcol] = wst1;
    *(float4*)&Xs[xk * 64 + xb]            = xst0;
    *(float4*)&Xs[(xk + 16) * 64 + xb]     = xst1;
    __syncthreads();
    if (s + 1 < NSTEPS) LOADG((s + 1) * BK);   // overlaps compute below

    float xr[32];
    #pragma unroll
    for (int kk = 0; kk < 32; ++kk) xr[kk] = Xs[kk * 64 + lane];

    #pragma unroll
    for (int r = 0; r < 16; ++r) {
      const float* wp = &Wt[(wv * 16 + r) * 32];
      float a = acc[r];
      #pragma unroll
      for (int kq = 0; kq < 8; ++kq) {
        float4 w = *(const float4*)(wp + kq * 4);   // broadcast b128
        a = fmaf(w.x, xr[kq * 4 + 0], a);
        a = fmaf(w.y, xr[kq * 4 + 1], a);
        a = fmaf(w.z, xr[kq * 4 + 2], a);
        a = fmaf(w.w, xr[kq * 4 + 3], a);
      }
      acc[r] = a;
    }
  }

  float* base = part + ((size_t)blockIdx.y * rows_total + r0 + wv * 16) * 64 + lane;
  #pragma unroll
  for (int r = 0; r < 16; ++r) base[(size_t)r * 64] = acc[r];   // 256B/instr
}

// ---------------------------------------------------------------------------
// Sum K-split partials + RoPE (half-split). q scaled by 1/sqrt(D).
// qkvf layout: q[64][32][128] | k[64][8][128] | v[64][8][128]
// ---------------------------------------------------------------------------
__global__ __launch_bounds__(256) void reduce_rope(
    const float* __restrict__ part, const float* __restrict__ cosT,
    const float* __restrict__ sinT, const int* __restrict__ positions,
    float* __restrict__ qkvf)
{
  const int bb  = threadIdx.x & 63;
  const int cid = blockIdx.x * 4 + (threadIdx.x >> 6);  // 0..3071
  const int pos = positions[bb];

  if (cid < 2048) {                       // q pairs: (hq, d0)
    const int hq = cid >> 6, d0 = cid & 63;
    const int r1 = hq * 128 + d0;
    float x1 = 0.f, x2 = 0.f;
    #pragma unroll 8
    for (int ks = 0; ks < KSPLIT; ++ks) {
      x1 += part[((size_t)ks * QKV_ROWS + r1) * 64 + bb];
      x2 += part[((size_t)ks * QKV_ROWS + r1 + 64) * 64 + bb];
    }
    float c = cosT[pos * 64 + d0], s = sinT[pos * 64 + d0];
    const float scale = 0.08838834764831843f;   // 1/sqrt(128)
    qkvf[(size_t)(bb * 32 + hq) * 128 + d0]      = (x1 * c - x2 * s) * scale;
    qkvf[(size_t)(bb * 32 + hq) * 128 + d0 + 64] = (x2 * c + x1 * s) * scale;
  } else if (cid < 2560) {                // k pairs
    const int c2 = cid - 2048;
    const int kh = c2 >> 6, d0 = c2 & 63;
    const int r1 = 4096 + kh * 128 + d0;
    float x1 = 0.f, x2 = 0.f;
    #pragma unroll 8
    for (int ks = 0; ks < KSPLIT; ++ks) {
      x1 += part[((size_t)ks * QKV_ROWS + r1) * 64 + bb];
      x2 += part[((size_t)ks * QKV_ROWS + r1 + 64) * 64 + bb];
    }
    float c = cosT[pos * 64 + d0], s = sinT[pos * 64 + d0];
    qkvf[262144 + (size_t)(bb * 8 + kh) * 128 + d0]      = x1 * c - x2 * s;
    qkvf[262144 + (size_t)(bb * 8 + kh) * 128 + d0 + 64] = x2 * c + x1 * s;
  } else {                                // v passthrough
    const int c2 = cid - 2560;
    const int kh = c2 >> 6, d0 = c2 & 63;
    const int r1 = 5120 + kh * 128 + d0;
    float x1 = 0.f, x2 = 0.f;
    #pragma unroll 8
    for (int ks = 0; ks < KSPLIT; ++ks) {
      x1 += part[((size_t)ks * QKV_ROWS + r1) * 64 + bb];
      x2 += part[((size_t)ks * QKV_ROWS + r1 + 64) * 64 + bb];
    }
    qkvf[327680 + (size_t)(bb * 8 + kh) * 128 + d0]      = x1;
    qkvf[327680 + (size_t)(bb * 8 + kh) * 128 + d0 + 64] = x2;
  }
}

// ---------------------------------------------------------------------------
// Flash-decode split attention: block = (b, h, split s). Each split handles
// chunk = ceil(ctx/8) tokens, emits unnormalized partial (m, l, sum pV).
// Token t == ctx-1 substitutes freshly-roped k/v (virtual cache scatter).
// ---------------------------------------------------------------------------
__global__ __launch_bounds__(256) void attn_split(
    const float* __restrict__ qkvf, const float* __restrict__ kcache,
    const float* __restrict__ vcache, const int* __restrict__ btab,
    const int* __restrict__ ctxlen,
    float* __restrict__ part_o,   // [B*HKV*SPLITS][4][128]
    float* __restrict__ part_ml)  // [B*HKV*SPLITS][4][2]
{
  const int bid = blockIdx.x;
  const int s   = bid & (SPLITS - 1);
  const int bh  = bid >> 3;
  const int b = bh >> 3, h = bh & 7;
  const int ctx   = ctxlen[b];
  const int chunk = (ctx + SPLITS - 1) / SPLITS;   // <= 128
  const int t0 = s * chunk;
  const int t1 = min(ctx, t0 + chunk);
  const int n  = t1 - t0;
  const int last = ctx - 1;

  const int tid  = threadIdx.x;
  const int half = tid >> 5;     // 0..7
  const int d4   = tid & 31;

  __shared__ float sc[4][128];
  __shared__ float oacc[8][4][128];
  __shared__ float red[4][2];    // m, l per group-head

  float4 qf[4];
  #pragma unroll
  for (int g = 0; g < 4; ++g)
    qf[g] = *(const float4*)(qkvf + (size_t)(b * 32 + h * 4 + g) * 128 + d4 * 4);

  const float* knew = qkvf + 262144 + (size_t)(b * 8 + h) * 128;
  const float* vnew = qkvf + 327680 + (size_t)(b * 8 + h) * 128;

  // ---- pass 1: scores for this chunk
  for (int t = t0 + half; t < t1; t += 8) {
    const float* kp;
    if (t == last) kp = knew;
    else {
      int slot = btab[b * MAXB_ + (t >> 4)] * BS_ + (t & 15);
      kp = kcache + ((size_t)slot * HKV_ + h) * D_;
    }
    float4 kv = *(const float4*)(kp + d4 * 4);
    float p0 = qf[0].x * kv.x + qf[0].y * kv.y + qf[0].z * kv.z + qf[0].w * kv.w;
    float p1 = qf[1].x * kv.x + qf[1].y * kv.y + qf[1].z * kv.z + qf[1].w * kv.w;
    float p2 = qf[2].x * kv.x + qf[2].y * kv.y + qf[2].z * kv.z + qf[2].w * kv.w;
    float p3 = qf[3].x * kv.x + qf[3].y * kv.y + qf[3].z * kv.z + qf[3].w * kv.w;
    #pragma unroll
    for (int m = 16; m >= 1; m >>= 1) {
      p0 += __shfl_xor(p0, m);
      p1 += __shfl_xor(p1, m);
      p2 += __shfl_xor(p2, m);
      p3 += __shfl_xor(p3, m);
    }
    if (d4 == 0) {
      int i = t - t0;
      sc[0][i] = p0; sc[1][i] = p1; sc[2][i] = p2; sc[3][i] = p3;
    }
  }
  __syncthreads();

  // ---- partial softmax: wave w handles group-head g = w
  {
    const int w = tid >> 6, l = tid & 63;
    float mx = -1e30f;
    for (int i = l; i < n; i += 64) mx = fmaxf(mx, sc[w][i]);
    #pragma unroll
    for (int m = 32; m >= 1; m >>= 1) mx = fmaxf(mx, __shfl_xor(mx, m));
    float lsum = 0.f;
    for (int i = l; i < n; i += 64) {
      float p = __expf(sc[w][i] - mx);
      sc[w][i] = p;
      lsum += p;
    }
    #pragma unroll
    for (int m = 32; m >= 1; m >>= 1) lsum += __shfl_xor(lsum, m);
    if (l == 0) { red[w][0] = mx; red[w][1] = lsum; }
  }
  __syncthreads();

  // ---- pass 2: sum p*V (unnormalized)
  float acc[4][4] = {{0.f}};
  for (int t = t0 + half; t < t1; t += 8) {
    const float* vp;
    if (t == last) vp = vnew;
    else {
      int slot = btab[b * MAXB_ + (t >> 4)] * BS_ + (t & 15);
      vp = vcache + ((size_t)slot * HKV_ + h) * D_;
    }
    float4 vv = *(const float4*)(vp + d4 * 4);
    int i = t - t0;
    #pragma unroll
    for (int g = 0; g < 4; ++g) {
      float p = sc[g][i];
      acc[g][0] += p * vv.x; acc[g][1] += p * vv.y;
      acc[g][2] += p * vv.z; acc[g][3] += p * vv.w;
    }
  }
  #pragma unroll
  for (int g = 0; g < 4; ++g)
    #pragma unroll
    for (int j = 0; j < 4; ++j)
      oacc[half][g][d4 * 4 + j] = acc[g][j];
  __syncthreads();

  for (int idx = tid; idx < 512; idx += 256) {
    int g = idx >> 7, d = idx & 127;
    float v = 0.f;
    #pragma unroll
    for (int hh = 0; hh < 8; ++hh) v += oacc[hh][g][d];
    part_o[(size_t)bid * 512 + idx] = v;
  }
  if (tid < 8) part_ml[(size_t)bid * 8 + tid] = red[tid >> 1][tid & 1];
}

// ---------------------------------------------------------------------------
// Combine split partials: out = sum_s exp(m_s-M) o_s / sum_s exp(m_s-M) l_s
// ---------------------------------------------------------------------------
__global__ __launch_bounds__(256) void attn_combine(
    const float* __restrict__ part_o, const float* __restrict__ part_ml,
    float* __restrict__ attn_out)
{
  const int bh = blockIdx.x;            // 0..511
  const int tid = threadIdx.x;

  __shared__ float Sg[SPLITS][4];
  __shared__ float Dg[4];

  if (tid < 32) {                       // lane = s*4+g
    int s = tid >> 2, g = tid & 3;
    float m = part_ml[((size_t)bh * SPLITS + s) * 8 + g * 2];
    float l = part_ml[((size_t)bh * SPLITS + s) * 8 + g * 2 + 1];
    float M = m;
    #pragma unroll
    for (int k = 4; k <= 16; k <<= 1) M = fmaxf(M, __shfl_xor(M, k));
    float scl = __expf(m - M);
    float dl = l * scl;
    #pragma unroll
    for (int k = 4; k <= 16; k <<= 1) dl += __shfl_xor(dl, k);
    Sg[s][g] = scl;
    if (s == 0) Dg[g] = dl;
  }
  __syncthreads();

  for (int idx = tid; idx < 512; idx += 256) {
    int g = idx >> 7;
    float num = 0.f;
    #pragma unroll
    for (int s = 0; s < SPLITS; ++s)
      num += Sg[s][g] * part_o[((size_t)bh * SPLITS + s) * 512 + idx];
    attn_out[(size_t)bh * 512 + idx] = num / Dg[g];
  }
}

// ---------------------------------------------------------------------------
// Sum K-split partials of O-GEMM ([ks][row][batch]) and write out[b][row]
// via LDS transpose: all global reads/writes coalesced.
// ---------------------------------------------------------------------------
__global__ __launch_bounds__(256) void reduce_out_t(
    const float* __restrict__ part, float* __restrict__ out)
{
  __shared__ float t[64][65];
  const int i0 = blockIdx.x * 64;
  const int lane = threadIdx.x & 63, q = threadIdx.x >> 6;

  #pragma unroll
  for (int rr = q; rr < 64; rr += 4) {
    float s = 0.f;
    #pragma unroll 8
    for (int ks = 0; ks < KSPLIT; ++ks)
      s += part[((size_t)ks * O_ROWS + i0 + rr) * 64 + lane];
    t[rr][lane] = s;
  }
  __syncthreads();
  #pragma unroll
  for (int rr = q; rr < 64; rr += 4)
    out[(size_t)rr * O_ROWS + i0 + lane] = t[lane][rr];
}

// ---------------------------------------------------------------------------
extern "C" void kernel_launch(void* const* d_in, const int* in_sizes, int n_in,
                              void* d_out, int out_size, void* d_ws, size_t ws_size,
                              hipStream_t stream)
{
  (void)in_sizes; (void)n_in; (void)out_size; (void)ws_size;
  const float* hidden    = (const float*)d_in[0];
  const int*   positions = (const int*)d_in[1];
  const float* cosT      = (const float*)d_in[2];
  const float* sinT      = (const float*)d_in[3];
  const float* kcache    = (const float*)d_in[4];
  const float* vcache    = (const float*)d_in[5];
  const int*   btab      = (const int*)d_in[7];
  const int*   ctx       = (const int*)d_in[8];
  const float* Wq        = (const float*)d_in[9];
  const float* Wk        = (const float*)d_in[10];
  const float* Wv        = (const float*)d_in[11];
  const float* Wo        = (const float*)d_in[12];
  float* out = (float*)d_out;

  float* ws      = (float*)d_ws;
  float* region  = ws;                       // reused 3x
  float* qkvf    = region + REGION_SZ;
  float* attn_o  = qkvf + QKVF_SZ;
  float* hiddenT = attn_o + ATTN_SZ;
  float* attn_oT = hiddenT + XT_SZ;
  // phase 1
  float* part1   = region;
  // phase 2 (after reduce_rope, part1 dead)
  float* part_o  = region;                                     // 4096*512
  float* part_ml = region + (size_t)B_ * HKV_ * SPLITS * 512;  // 4096*8
  // phase 3 (after attn_combine, part_o dead)
  float* part3   = region;

  transpose64<<<HID_ / 64, 256, 0, stream>>>(hidden, hiddenT, HID_);
  gemm_lds<<<dim3(QKV_ROWS / 64, KSPLIT), 256, 0, stream>>>(
      hiddenT, Wq, Wk, Wv, 4096, 5120, QKV_ROWS, part1);
  reduce_rope<<<768, 256, 0, stream>>>(part1, cosT, sinT, positions, qkvf);
  attn_split<<<B_ * HKV_ * SPLITS, 256, 0, stream>>>(
      qkvf, kcache, vcache, btab, ctx, part_o, part_ml);
  attn_combine<<<B_ * HKV_, 256, 0, stream>>>(part_o, part_ml, attn_o);
  transpose64<<<O_ROWS / 64, 256, 0, stream>>>(attn_o, attn_oT, O_ROWS);
  gemm_lds<<<dim3(O_ROWS / 64, KSPLIT), 256, 0, stream>>>(
      attn_oT, Wo, Wo, Wo, O_ROWS, O_ROWS, O_ROWS, part3);
  reduce_out_t<<<O_ROWS / 64, 256, 0, stream>>>(part3, out);
}

// Round 8
// 203.415 us; speedup vs baseline: 4.0175x; 1.5992x over previous
//
#include <hip/hip_runtime.h>

#define B_    64
#define HID_  4096
#define HQ_   32
#define HKV_  8
#define D_    128
#define BS_   16
#define MAXB_ 64

#define KSPLIT  16
#define KCHUNK  (HID_ / KSPLIT)   // 256
#define QKV_ROWS 6144             // 4096 q + 1024 k + 1024 v
#define O_ROWS   4096
#define SPLITS  8                 // flash-decode token splits

#define REGION_SZ ((size_t)KSPLIT * QKV_ROWS * 64)
#define QKVF_SZ  ((size_t)64 * 6144)
#define ATTN_SZ  ((size_t)64 * 4096)
#define XB_SZ    ((size_t)HID_ * 64)   // ushort count per XB buffer

typedef __attribute__((ext_vector_type(8))) short bf16x8;
typedef __attribute__((ext_vector_type(4))) float f32x4;

__device__ inline unsigned short f2bf(float x) {
  union { float f; unsigned u; } v; v.f = x;
  unsigned r = v.u + 0x7fff + ((v.u >> 16) & 1);   // RNE
  return (unsigned short)(r >> 16);
}
__device__ inline float bf2f(unsigned short h) {
  union { float f; unsigned u; } v; v.u = ((unsigned)h) << 16; return v.f;
}

// ---------------------------------------------------------------------------
// Convert X [64][HID] fp32 -> fragment-contiguous bf16 hi/lo:
// XB[kg][b][j] = bf16(X[b][kg*8+j]), j contiguous (16B per (kg,b)).
// B-fragment load is then one coalesced 16B read per lane.
// ---------------------------------------------------------------------------
__global__ __launch_bounds__(256) void convert_x(
    const float* __restrict__ X, unsigned short* __restrict__ XBhi,
    unsigned short* __restrict__ XBlo)
{
  int idx = blockIdx.x * 256 + threadIdx.x;   // 0..32767
  int kg = idx >> 6, b = idx & 63;
  const float* xp = X + (size_t)b * HID_ + kg * 8;
  float4 a = *(const float4*)xp, c = *(const float4*)(xp + 4);
  float xs[8] = {a.x, a.y, a.z, a.w, c.x, c.y, c.z, c.w};
  unsigned short hi[8], lo[8];
  #pragma unroll
  for (int j = 0; j < 8; ++j) {
    hi[j] = f2bf(xs[j]);
    lo[j] = f2bf(xs[j] - bf2f(hi[j]));
  }
  *(uint4*)(XBhi + (size_t)idx * 8) = *(const uint4*)hi;
  *(uint4*)(XBlo + (size_t)idx * 8) = *(const uint4*)lo;
}

// ---------------------------------------------------------------------------
// Split-bf16 MFMA skinny GEMM partial: C[row][batch] = W x X^T.
// Wave = 32 rows x 64 batches (2 A-row-tiles x 4 B-col-tiles of 16x16x32).
// A (W) loaded fp32 direct from global (each byte read once), converted
// in-register to hi/lo bf16; B from pre-converted XB (L2-resident).
// 3 MFMA terms: hi*hi + lo*hi + hi*lo  (lo*lo ~ 2^-16 rel, dropped).
// part[ks][row][64batch].
// ---------------------------------------------------------------------------
__global__ __launch_bounds__(256, 4) void gemm_mfma(
    const float* __restrict__ W0, const float* __restrict__ W1,
    const float* __restrict__ W2,
    const unsigned short* __restrict__ XBhi,
    const unsigned short* __restrict__ XBlo,
    int split1, int split2, int rows_total, float* __restrict__ part)
{
  const int tid = threadIdx.x;
  const int l   = tid & 63;
  const int w   = tid >> 6;               // wave 0..3
  const int r0  = blockIdx.x * 128 + w * 32;
  const int k0  = blockIdx.y * KCHUNK;

  const float* W; int rloc;
  if (r0 < split1)      { W = W0; rloc = r0; }
  else if (r0 < split2) { W = W1; rloc = r0 - split1; }
  else                  { W = W2; rloc = r0 - split2; }

  const int lm = l & 15;                  // M / N index within 16-tile
  const int lk = l >> 4;                  // k-group 0..3 (8 k each)

  const float* wp0 = W + (size_t)(rloc + lm) * HID_ + k0 + lk * 8;
  const float* wp1 = wp0 + (size_t)16 * HID_;
  const unsigned short* bh = XBhi + ((size_t)(k0 / 8 + lk) * 64 + lm) * 8;
  const unsigned short* bl = XBlo + ((size_t)(k0 / 8 + lk) * 64 + lm) * 8;

  f32x4 acc[2][4];
  #pragma unroll
  for (int rt = 0; rt < 2; ++rt)
    #pragma unroll
    for (int ct = 0; ct < 4; ++ct)
      #pragma unroll
      for (int i = 0; i < 4; ++i) acc[rt][ct][i] = 0.f;

  #pragma unroll 2
  for (int ks = 0; ks < KCHUNK / 32; ++ks) {
    // B fragments: 4 col-tiles, hi+lo (coalesced 16B/lane, L2 hits)
    bf16x8 Bh[4], Bl[4];
    #pragma unroll
    for (int ct = 0; ct < 4; ++ct) {
      Bh[ct] = *(const bf16x8*)(bh + (size_t)ks * 2048 + ct * 128);
      Bl[ct] = *(const bf16x8*)(bl + (size_t)ks * 2048 + ct * 128);
    }
    #pragma unroll
    for (int rt = 0; rt < 2; ++rt) {
      const float* wp = (rt ? wp1 : wp0) + ks * 32;
      float4 a0 = *(const float4*)wp;
      float4 a1 = *(const float4*)(wp + 4);
      float xs[8] = {a0.x, a0.y, a0.z, a0.w, a1.x, a1.y, a1.z, a1.w};
      bf16x8 Ah, Al;
      #pragma unroll
      for (int j = 0; j < 8; ++j) {
        unsigned short h = f2bf(xs[j]);
        Ah[j] = (short)h;
        Al[j] = (short)f2bf(xs[j] - bf2f(h));
      }
      #pragma unroll
      for (int ct = 0; ct < 4; ++ct) {
        acc[rt][ct] = __builtin_amdgcn_mfma_f32_16x16x32_bf16(Ah, Bh[ct], acc[rt][ct], 0, 0, 0);
        acc[rt][ct] = __builtin_amdgcn_mfma_f32_16x16x32_bf16(Al, Bh[ct], acc[rt][ct], 0, 0, 0);
        acc[rt][ct] = __builtin_amdgcn_mfma_f32_16x16x32_bf16(Ah, Bl[ct], acc[rt][ct], 0, 0, 0);
      }
    }
  }

  // C layout: col = lane&15, row = (lane>>4)*4 + reg
  #pragma unroll
  for (int rt = 0; rt < 2; ++rt)
    #pragma unroll
    for (int ct = 0; ct < 4; ++ct) {
      int row = r0 + rt * 16 + lk * 4;
      int bat = ct * 16 + lm;
      #pragma unroll
      for (int i = 0; i < 4; ++i)
        part[((size_t)blockIdx.y * rows_total + row + i) * 64 + bat] = acc[rt][ct][i];
    }
}

// ---------------------------------------------------------------------------
// Sum K-split partials + RoPE (half-split). q scaled by 1/sqrt(D).
// qkvf layout: q[64][32][128] | k[64][8][128] | v[64][8][128]
// ---------------------------------------------------------------------------
__global__ __launch_bounds__(256) void reduce_rope(
    const float* __restrict__ part, const float* __restrict__ cosT,
    const float* __restrict__ sinT, const int* __restrict__ positions,
    float* __restrict__ qkvf)
{
  const int bb  = threadIdx.x & 63;
  const int cid = blockIdx.x * 4 + (threadIdx.x >> 6);  // 0..3071
  const int pos = positions[bb];

  if (cid < 2048) {                       // q pairs: (hq, d0)
    const int hq = cid >> 6, d0 = cid & 63;
    const int r1 = hq * 128 + d0;
    float x1 = 0.f, x2 = 0.f;
    #pragma unroll 8
    for (int ks = 0; ks < KSPLIT; ++ks) {
      x1 += part[((size_t)ks * QKV_ROWS + r1) * 64 + bb];
      x2 += part[((size_t)ks * QKV_ROWS + r1 + 64) * 64 + bb];
    }
    float c = cosT[pos * 64 + d0], s = sinT[pos * 64 + d0];
    const float scale = 0.08838834764831843f;   // 1/sqrt(128)
    qkvf[(size_t)(bb * 32 + hq) * 128 + d0]      = (x1 * c - x2 * s) * scale;
    qkvf[(size_t)(bb * 32 + hq) * 128 + d0 + 64] = (x2 * c + x1 * s) * scale;
  } else if (cid < 2560) {                // k pairs
    const int c2 = cid - 2048;
    const int kh = c2 >> 6, d0 = c2 & 63;
    const int r1 = 4096 + kh * 128 + d0;
    float x1 = 0.f, x2 = 0.f;
    #pragma unroll 8
    for (int ks = 0; ks < KSPLIT; ++ks) {
      x1 += part[((size_t)ks * QKV_ROWS + r1) * 64 + bb];
      x2 += part[((size_t)ks * QKV_ROWS + r1 + 64) * 64 + bb];
    }
    float c = cosT[pos * 64 + d0], s = sinT[pos * 64 + d0];
    qkvf[262144 + (size_t)(bb * 8 + kh) * 128 + d0]      = x1 * c - x2 * s;
    qkvf[262144 + (size_t)(bb * 8 + kh) * 128 + d0 + 64] = x2 * c + x1 * s;
  } else {                                // v passthrough
    const int c2 = cid - 2560;
    const int kh = c2 >> 6, d0 = c2 & 63;
    const int r1 = 5120 + kh * 128 + d0;
    float x1 = 0.f, x2 = 0.f;
    #pragma unroll 8
    for (int ks = 0; ks < KSPLIT; ++ks) {
      x1 += part[((size_t)ks * QKV_ROWS + r1) * 64 + bb];
      x2 += part[((size_t)ks * QKV_ROWS + r1 + 64) * 64 + bb];
    }
    qkvf[327680 + (size_t)(bb * 8 + kh) * 128 + d0]      = x1;
    qkvf[327680 + (size_t)(bb * 8 + kh) * 128 + d0 + 64] = x2;
  }
}

// ---------------------------------------------------------------------------
// Flash-decode split attention (unchanged from round 7).
// ---------------------------------------------------------------------------
__global__ __launch_bounds__(256) void attn_split(
    const float* __restrict__ qkvf, const float* __restrict__ kcache,
    const float* __restrict__ vcache, const int* __restrict__ btab,
    const int* __restrict__ ctxlen,
    float* __restrict__ part_o,   // [B*HKV*SPLITS][4][128]
    float* __restrict__ part_ml)  // [B*HKV*SPLITS][4][2]
{
  const int bid = blockIdx.x;
  const int s   = bid & (SPLITS - 1);
  const int bh  = bid >> 3;
  const int b = bh >> 3, h = bh & 7;
  const int ctx   = ctxlen[b];
  const int chunk = (ctx + SPLITS - 1) / SPLITS;   // <= 128
  const int t0 = s * chunk;
  const int t1 = min(ctx, t0 + chunk);
  const int n  = t1 - t0;
  const int last = ctx - 1;

  const int tid  = threadIdx.x;
  const int half = tid >> 5;     // 0..7
  const int d4   = tid & 31;

  __shared__ float sc[4][128];
  __shared__ float oacc[8][4][128];
  __shared__ float red[4][2];    // m, l per group-head

  float4 qf[4];
  #pragma unroll
  for (int g = 0; g < 4; ++g)
    qf[g] = *(const float4*)(qkvf + (size_t)(b * 32 + h * 4 + g) * 128 + d4 * 4);

  const float* knew = qkvf + 262144 + (size_t)(b * 8 + h) * 128;
  const float* vnew = qkvf + 327680 + (size_t)(b * 8 + h) * 128;

  for (int t = t0 + half; t < t1; t += 8) {
    const float* kp;
    if (t == last) kp = knew;
    else {
      int slot = btab[b * MAXB_ + (t >> 4)] * BS_ + (t & 15);
      kp = kcache + ((size_t)slot * HKV_ + h) * D_;
    }
    float4 kv = *(const float4*)(kp + d4 * 4);
    float p0 = qf[0].x * kv.x + qf[0].y * kv.y + qf[0].z * kv.z + qf[0].w * kv.w;
    float p1 = qf[1].x * kv.x + qf[1].y * kv.y + qf[1].z * kv.z + qf[1].w * kv.w;
    float p2 = qf[2].x * kv.x + qf[2].y * kv.y + qf[2].z * kv.z + qf[2].w * kv.w;
    float p3 = qf[3].x * kv.x + qf[3].y * kv.y + qf[3].z * kv.z + qf[3].w * kv.w;
    #pragma unroll
    for (int m = 16; m >= 1; m >>= 1) {
      p0 += __shfl_xor(p0, m);
      p1 += __shfl_xor(p1, m);
      p2 += __shfl_xor(p2, m);
      p3 += __shfl_xor(p3, m);
    }
    if (d4 == 0) {
      int i = t - t0;
      sc[0][i] = p0; sc[1][i] = p1; sc[2][i] = p2; sc[3][i] = p3;
    }
  }
  __syncthreads();

  {
    const int w = tid >> 6, l = tid & 63;
    float mx = -1e30f;
    for (int i = l; i < n; i += 64) mx = fmaxf(mx, sc[w][i]);
    #pragma unroll
    for (int m = 32; m >= 1; m >>= 1) mx = fmaxf(mx, __shfl_xor(mx, m));
    float lsum = 0.f;
    for (int i = l; i < n; i += 64) {
      float p = __expf(sc[w][i] - mx);
      sc[w][i] = p;
      lsum += p;
    }
    #pragma unroll
    for (int m = 32; m >= 1; m >>= 1) lsum += __shfl_xor(lsum, m);
    if (l == 0) { red[w][0] = mx; red[w][1] = lsum; }
  }
  __syncthreads();

  float acc[4][4] = {{0.f}};
  for (int t = t0 + half; t < t1; t += 8) {
    const float* vp;
    if (t == last) vp = vnew;
    else {
      int slot = btab[b * MAXB_ + (t >> 4)] * BS_ + (t & 15);
      vp = vcache + ((size_t)slot * HKV_ + h) * D_;
    }
    float4 vv = *(const float4*)(vp + d4 * 4);
    int i = t - t0;
    #pragma unroll
    for (int g = 0; g < 4; ++g) {
      float p = sc[g][i];
      acc[g][0] += p * vv.x; acc[g][1] += p * vv.y;
      acc[g][2] += p * vv.z; acc[g][3] += p * vv.w;
    }
  }
  #pragma unroll
  for (int g = 0; g < 4; ++g)
    #pragma unroll
    for (int j = 0; j < 4; ++j)
      oacc[half][g][d4 * 4 + j] = acc[g][j];
  __syncthreads();

  for (int idx = tid; idx < 512; idx += 256) {
    int g = idx >> 7, d = idx & 127;
    float v = 0.f;
    #pragma unroll
    for (int hh = 0; hh < 8; ++hh) v += oacc[hh][g][d];
    part_o[(size_t)bid * 512 + idx] = v;
  }
  if (tid < 8) part_ml[(size_t)bid * 8 + tid] = red[tid >> 1][tid & 1];
}

// ---------------------------------------------------------------------------
__global__ __launch_bounds__(256) void attn_combine(
    const float* __restrict__ part_o, const float* __restrict__ part_ml,
    float* __restrict__ attn_out)
{
  const int bh = blockIdx.x;            // 0..511
  const int tid = threadIdx.x;

  __shared__ float Sg[SPLITS][4];
  __shared__ float Dg[4];

  if (tid < 32) {                       // lane = s*4+g
    int s = tid >> 2, g = tid & 3;
    float m = part_ml[((size_t)bh * SPLITS + s) * 8 + g * 2];
    float l = part_ml[((size_t)bh * SPLITS + s) * 8 + g * 2 + 1];
    float M = m;
    #pragma unroll
    for (int k = 4; k <= 16; k <<= 1) M = fmaxf(M, __shfl_xor(M, k));
    float scl = __expf(m - M);
    float dl = l * scl;
    #pragma unroll
    for (int k = 4; k <= 16; k <<= 1) dl += __shfl_xor(dl, k);
    Sg[s][g] = scl;
    if (s == 0) Dg[g] = dl;
  }
  __syncthreads();

  for (int idx = tid; idx < 512; idx += 256) {
    int g = idx >> 7;
    float num = 0.f;
    #pragma unroll
    for (int s = 0; s < SPLITS; ++s)
      num += Sg[s][g] * part_o[((size_t)bh * SPLITS + s) * 512 + idx];
    attn_out[(size_t)bh * 512 + idx] = num / Dg[g];
  }
}

// ---------------------------------------------------------------------------
// Sum K-split partials of O-GEMM ([ks][row][batch]) -> out[b][row] via LDS
// transpose, coalesced both sides.
// ---------------------------------------------------------------------------
__global__ __launch_bounds__(256) void reduce_out_t(
    const float* __restrict__ part, float* __restrict__ out)
{
  __shared__ float t[64][65];
  const int i0 = blockIdx.x * 64;
  const int lane = threadIdx.x & 63, q = threadIdx.x >> 6;

  #pragma unroll
  for (int rr = q; rr < 64; rr += 4) {
    float s = 0.f;
    #pragma unroll 8
    for (int ks = 0; ks < KSPLIT; ++ks)
      s += part[((size_t)ks * O_ROWS + i0 + rr) * 64 + lane];
    t[rr][lane] = s;
  }
  __syncthreads();
  #pragma unroll
  for (int rr = q; rr < 64; rr += 4)
    out[(size_t)rr * O_ROWS + i0 + lane] = t[lane][rr];
}

// ---------------------------------------------------------------------------
extern "C" void kernel_launch(void* const* d_in, const int* in_sizes, int n_in,
                              void* d_out, int out_size, void* d_ws, size_t ws_size,
                              hipStream_t stream)
{
  (void)in_sizes; (void)n_in; (void)out_size; (void)ws_size;
  const float* hidden    = (const float*)d_in[0];
  const int*   positions = (const int*)d_in[1];
  const float* cosT      = (const float*)d_in[2];
  const float* sinT      = (const float*)d_in[3];
  const float* kcache    = (const float*)d_in[4];
  const float* vcache    = (const float*)d_in[5];
  const int*   btab      = (const int*)d_in[7];
  const int*   ctx       = (const int*)d_in[8];
  const float* Wq        = (const float*)d_in[9];
  const float* Wk        = (const float*)d_in[10];
  const float* Wv        = (const float*)d_in[11];
  const float* Wo        = (const float*)d_in[12];
  float* out = (float*)d_out;

  float* ws      = (float*)d_ws;
  float* region  = ws;                       // reused 3x
  float* qkvf    = region + REGION_SZ;
  float* attn_o  = qkvf + QKVF_SZ;
  unsigned short* XBhi = (unsigned short*)(attn_o + ATTN_SZ);
  unsigned short* XBlo = XBhi + XB_SZ;
  // phase 1
  float* part1   = region;
  // phase 2 (after reduce_rope, part1 dead)
  float* part_o  = region;                                     // 4096*512
  float* part_ml = region + (size_t)B_ * HKV_ * SPLITS * 512;  // 4096*8
  // phase 3 (after attn_combine, part_o dead)
  float* part3   = region;

  convert_x<<<128, 256, 0, stream>>>(hidden, XBhi, XBlo);
  gemm_mfma<<<dim3(QKV_ROWS / 128, KSPLIT), 256, 0, stream>>>(
      Wq, Wk, Wv, XBhi, XBlo, 4096, 5120, QKV_ROWS, part1);
  reduce_rope<<<768, 256, 0, stream>>>(part1, cosT, sinT, positions, qkvf);
  attn_split<<<B_ * HKV_ * SPLITS, 256, 0, stream>>>(
      qkvf, kcache, vcache, btab, ctx, part_o, part_ml);
  attn_combine<<<B_ * HKV_, 256, 0, stream>>>(part_o, part_ml, attn_o);
  convert_x<<<128, 256, 0, stream>>>(attn_o, XBhi, XBlo);
  gemm_mfma<<<dim3(O_ROWS / 128, KSPLIT), 256, 0, stream>>>(
      Wo, Wo, Wo, XBhi, XBlo, O_ROWS, O_ROWS, O_ROWS, part3);
  reduce_out_t<<<O_ROWS / 64, 256, 0, stream>>>(part3, out);
}